// Round 3
// baseline (549.899 us; speedup 1.0000x reference)
//
#include <hip/hip_runtime.h>

#define N_NODES 200000
#define N_EDGES 1200000
#define F_IN    64
#define F_H     128
#define BN_EPS  1e-5f
#define NBUK    196          // ceil(N/1024) dst-buckets of 1024 nodes
#define BINB    293          // ceil(E/4096) bin blocks
#define GGRID   512          // persistent gemm grid: 2 blocks/CU x 256 CU

typedef short bf16x8 __attribute__((ext_vector_type(8)));   // 8 bf16 in 4 VGPRs
typedef float f32x4  __attribute__((ext_vector_type(4)));
typedef unsigned short us4 __attribute__((ext_vector_type(4)));

__device__ __forceinline__ unsigned short f2bf(float f) {
    union { float f; unsigned u; } v; v.f = f;
    unsigned r = (v.u + 0x7FFFu + ((v.u >> 16) & 1u)) >> 16;  // RNE
    return (unsigned short)r;
}
__device__ __forceinline__ float bf2f(unsigned short b) {
    union { unsigned u; float f; } v; v.u = ((unsigned)b) << 16;
    return v.f;
}

// ---------------------------------------------------------------------------
// Weight pack into bf16 MFMA B-fragment order for mfma_f32_16x16x32_bf16.
// ---------------------------------------------------------------------------
__global__ void pack_weights_kernel(const float* __restrict__ W,
                                    const float* __restrict__ kscale,
                                    short* __restrict__ P, int KT)
{
    int t = blockIdx.x * 256 + threadIdx.x;            // over 8*KT*64
    if (t >= 8 * KT * 64) return;
    int lane = t & 63;
    int kt   = (t >> 6) % KT;
    int nt   = t / (64 * KT);
    int k0   = kt * 32 + (lane >> 4) * 8;
    int n    = nt * 16 + (lane & 15);
#pragma unroll
    for (int j = 0; j < 8; ++j) {
        float w = W[(size_t)(k0 + j) * 128 + n];
        if (kscale) w *= kscale[k0 + j];
        P[(size_t)t * 8 + j] = (short)f2bf(w);
    }
}

// ---------------------------------------------------------------------------
// CSR build: histogram -> 2-level exclusive scan over deg -> bucketed fill
// ---------------------------------------------------------------------------
__global__ __launch_bounds__(256) void hist_kernel(const int* __restrict__ ei,
                                                   int* __restrict__ deg, int E)
{
    int e = blockIdx.x * 256 + threadIdx.x;
    if (e < E) atomicAdd(&deg[ei[E + e]], 1);
}

__global__ __launch_bounds__(256) void scan1_kernel(const int* __restrict__ deg,
        int* __restrict__ part, int* __restrict__ bsum, int n)
{
    __shared__ int s[256];
    int t = threadIdx.x;
    int base = blockIdx.x * 1024 + t * 4;
    int v[4];
#pragma unroll
    for (int j = 0; j < 4; ++j) v[j] = (base + j < n) ? deg[base + j] : 0;
    int tsum = v[0] + v[1] + v[2] + v[3];
    s[t] = tsum;
    __syncthreads();
    for (int off = 1; off < 256; off <<= 1) {
        int xv = (t >= off) ? s[t - off] : 0;
        __syncthreads();
        s[t] += xv;
        __syncthreads();
    }
    int excl = s[t] - tsum;
#pragma unroll
    for (int j = 0; j < 4; ++j) {
        if (base + j < n) part[base + j] = excl;
        excl += v[j];
    }
    if (t == 255) bsum[blockIdx.x] = s[255];
}

__global__ void scan2_kernel(int* __restrict__ bsum, int nb)
{
    __shared__ int s[256];
    int t = threadIdx.x;
    int v = (t < nb) ? bsum[t] : 0;
    s[t] = v;
    __syncthreads();
    for (int off = 1; off < 256; off <<= 1) {
        int xv = (t >= off) ? s[t - off] : 0;
        __syncthreads();
        s[t] += xv;
        __syncthreads();
    }
    if (t < nb) bsum[t] = s[t] - v;   // exclusive
}

__global__ __launch_bounds__(256) void scan3_kernel(
    const int* __restrict__ part, const int* __restrict__ bsum,
    const int* __restrict__ deg, int* __restrict__ rowptr,
    int* __restrict__ bcursor, float* __restrict__ degf, int n, int E)
{
    int i = blockIdx.x * 256 + threadIdx.x;
    if (i == 0) rowptr[n] = E;
    if (i >= n) return;
    int r = part[i] + bsum[i >> 10];
    rowptr[i] = r;
    if ((i & 1023) == 0) bcursor[i >> 10] = r;   // bucket segment base
    degf[i]   = (float)deg[i];
}

// ---------------------------------------------------------------------------
// bin_kernel: LDS multi-split of edges into 196 contiguous-dst buckets.
// ---------------------------------------------------------------------------
__global__ __launch_bounds__(256) void bin_kernel(
    const int* __restrict__ ei, int* __restrict__ bcursor,
    unsigned* __restrict__ binned, int E)
{
    __shared__ int lcnt[256];
    __shared__ int lbase[256];
    __shared__ int gbase[256];
    __shared__ int sc[256];
    __shared__ unsigned stage[4096];
    __shared__ unsigned char stgb[4096];
    const int tid  = threadIdx.x;
    const int base = blockIdx.x * 4096;
    lcnt[tid] = 0;
    __syncthreads();

    unsigned val[16]; short lp[16]; unsigned char bk[16];
#pragma unroll
    for (int i = 0; i < 16; ++i) {
        int e = base + i * 256 + tid;
        if (e < E) {
            int s = ei[e], d = ei[E + e];
            int b = d >> 10;
            val[i] = ((unsigned)s << 10) | (unsigned)(d & 1023);
            bk[i]  = (unsigned char)b;
            lp[i]  = (short)atomicAdd(&lcnt[b], 1);
        } else lp[i] = -1;
    }
    __syncthreads();

    // exclusive scan of per-bucket counts + global range reservation
    int c = lcnt[tid];
    sc[tid] = c;
    __syncthreads();
    for (int off = 1; off < 256; off <<= 1) {
        int v = (tid >= off) ? sc[tid - off] : 0;
        __syncthreads();
        sc[tid] += v;
        __syncthreads();
    }
    lbase[tid] = sc[tid] - c;
    if (c) gbase[tid] = atomicAdd(&bcursor[tid], c);
    __syncthreads();
    const int total = sc[255];

    // bucket-sorted stage in LDS
#pragma unroll
    for (int i = 0; i < 16; ++i) {
        if (lp[i] >= 0) {
            int p = lbase[bk[i]] + lp[i];
            stage[p] = val[i];
            stgb[p]  = bk[i];
        }
    }
    __syncthreads();

    // write out: consecutive p within a bucket -> consecutive global addrs
    for (int p = tid; p < total; p += 256) {
        int b = stgb[p];
        binned[gbase[b] + (p - lbase[b])] = stage[p];
    }
}

// ---------------------------------------------------------------------------
// scatter_kernel: one block per bucket; LDS cursors; writes stay in-bucket.
// ---------------------------------------------------------------------------
__global__ __launch_bounds__(256) void scatter_kernel(
    const unsigned* __restrict__ binned, const int* __restrict__ rowptr,
    int* __restrict__ ssrc)
{
    __shared__ int cur[1024];
    const int b    = blockIdx.x;
    const int tid  = threadIdx.x;
    const int dbase = b << 10;
    const int dmax  = min(1024, N_NODES - dbase);
    for (int j = tid; j < dmax; j += 256) cur[j] = rowptr[dbase + j];
    __syncthreads();
    const int s0 = rowptr[dbase];
    const int s1 = rowptr[dbase + dmax];
    for (int e = s0 + tid; e < s1; e += 256) {
        unsigned v = binned[e];
        int pos = atomicAdd(&cur[v & 1023u], 1);
        ssrc[pos] = (int)(v >> 10);
    }
}

// ---------------------------------------------------------------------------
// Gather layer 1: aggb[row,0:64] = bf16( sum_src x[src,:] ).
// ---------------------------------------------------------------------------
__global__ __launch_bounds__(256) void gather1_kernel(
    const float* __restrict__ x, const int* __restrict__ rowptr,
    const int* __restrict__ ssrc, unsigned short* __restrict__ aggb)
{
    const int tid  = threadIdx.x;
    const int wv   = tid >> 6;
    const int lane = tid & 63;
    const int sub  = lane >> 4;
    const int li   = lane & 15;
    const int row  = blockIdx.x * 16 + wv * 4 + sub;

    const int b = rowptr[row], e = rowptr[row + 1];
    float4 acc = {0.f, 0.f, 0.f, 0.f};
    int s[8];
#pragma unroll
    for (int q = 0; q < 8; ++q) s[q] = (b + q < e) ? ssrc[b + q] : row;
    for (int j = b; j < e; j += 8) {
        int nn[8];
        const int jn = j + 8;
#pragma unroll
        for (int q = 0; q < 8; ++q) nn[q] = (jn + q < e) ? ssrc[jn + q] : row;
        float4 v[8];
#pragma unroll
        for (int q = 0; q < 8; ++q)
            v[q] = ((const float4*)(x + (size_t)s[q] * F_IN))[li];
#pragma unroll
        for (int q = 0; q < 8; ++q) {
            float w = (j + q < e) ? 1.f : 0.f;
            acc.x = fmaf(v[q].x, w, acc.x);
            acc.y = fmaf(v[q].y, w, acc.y);
            acc.z = fmaf(v[q].z, w, acc.z);
            acc.w = fmaf(v[q].w, w, acc.w);
        }
#pragma unroll
        for (int q = 0; q < 8; ++q) s[q] = nn[q];
    }
    us4 o;
    o.x = f2bf(acc.x); o.y = f2bf(acc.y); o.z = f2bf(acc.z); o.w = f2bf(acc.w);
    *(us4*)(aggb + (size_t)row * F_IN + li * 4) = o;
}

// ---------------------------------------------------------------------------
// Gather layer 2: aggb[row,0:128] = bf16( sum_src t1[src,:] ), batch x8.
// ---------------------------------------------------------------------------
__global__ __launch_bounds__(256) void gather2_kernel(
    const unsigned short* __restrict__ t1, const int* __restrict__ rowptr,
    const int* __restrict__ ssrc, unsigned short* __restrict__ aggb)
{
    const int tid  = threadIdx.x;
    const int wv   = tid >> 6;
    const int lane = tid & 63;
    const int sub  = lane >> 4;
    const int li   = lane & 15;
    const int row  = blockIdx.x * 16 + wv * 4 + sub;

    const int b = rowptr[row], e = rowptr[row + 1];
    float acc[8] = {};
    int s[8];
#pragma unroll
    for (int q = 0; q < 8; ++q) s[q] = (b + q < e) ? ssrc[b + q] : row;
    for (int j = b; j < e; j += 8) {
        int nn[8];
        const int jn = j + 8;
#pragma unroll
        for (int q = 0; q < 8; ++q) nn[q] = (jn + q < e) ? ssrc[jn + q] : row;
        bf16x8 v[8];
#pragma unroll
        for (int q = 0; q < 8; ++q)
            v[q] = *(const bf16x8*)(t1 + (size_t)s[q] * F_H + li * 8);
#pragma unroll
        for (int q = 0; q < 8; ++q) {
            float w = (j + q < e) ? 1.f : 0.f;
#pragma unroll
            for (int k = 0; k < 8; ++k)
                acc[k] = fmaf(bf2f((unsigned short)v[q][k]), w, acc[k]);
        }
#pragma unroll
        for (int q = 0; q < 8; ++q) s[q] = nn[q];
    }
    bf16x8 o;
#pragma unroll
    for (int k = 0; k < 8; ++k) o[k] = (short)f2bf(acc[k]);
    *(bf16x8*)(aggb + (size_t)row * F_H + li * 8) = o;
}

// ---------------------------------------------------------------------------
// Persistent MFMA GEMM (R3): grid = 512 (2 blocks/CU), each block stages
// weights in LDS ONCE, then grid-strides over ~3 row-tiles of 128 rows with
// a 2-deep register double-buffer: tile i+1's A/X loads are issued BEFORE
// tile i's compute, keeping HBM loads continuously in flight. No barriers
// in the tile loop (weight LDS is read-only). BN stats accumulate in
// registers across tiles; single LDS+global reduce at block end.
// Rationale: R2's per-tile-block version was latency-bound at 1.57 TB/s —
// each block's load phase idled the memory system between blocks (LDS
// staging change was neutral; phases, not weights, were the cost).
// ---------------------------------------------------------------------------
template<int K, bool L2>
__global__ __launch_bounds__(256, 2) void gemm_mfma_kernel(
    const unsigned short* __restrict__ Ab,
    const float* __restrict__ Xf,
    const unsigned short* __restrict__ Xb,
    const bf16x8* __restrict__ Wlp, const bf16x8* __restrict__ Wrp,
    const float* __restrict__ bias,
    const float* __restrict__ c2, const float* __restrict__ degf,
    float* __restrict__ outF, unsigned short* __restrict__ outB,
    float* __restrict__ gsum, float* __restrict__ gsq)
{
    constexpr int KT = K / 32;
    constexpr int WHALF = 8 * KT * 64 * 8;        // shorts per weight array
    constexpr int NT = (N_NODES + 127) / 128;     // 1563 row-tiles
    __shared__ short sW[2 * WHALF];               // Wl | Wr (stats overlaid later)

    const int tid  = threadIdx.x;
    const int lane = tid & 63;
    const int wv   = tid >> 6;
    const int m    = lane & 15;
    const int quad = lane >> 4;

    // ---- stage packed weights into LDS (cooperative, once per block) ----
    {
        const short* wl = (const short*)Wlp;
        const short* wr = (const short*)Wrp;
#pragma unroll
        for (int i = 0; i < WHALF / (256 * 8); ++i) {
            int idx = (i * 256 + tid) * 8;
            *(bf16x8*)(sW + idx)         = *(const bf16x8*)(wl + idx);
            *(bf16x8*)(sW + WHALF + idx) = *(const bf16x8*)(wr + idx);
        }
    }

    // per-nt epilogue constants (col = nt*16 + m)
    float bcol[8], ccol[8];
#pragma unroll
    for (int nt = 0; nt < 8; ++nt) {
        bcol[nt] = bias[nt * 16 + m];
        if constexpr (L2) ccol[nt] = c2[nt * 16 + m];
    }

    float stS[8] = {}, stQ[8] = {};   // BN stats, accumulated across tiles

    __syncthreads();   // weights visible to all waves

    const short* wlL = sW + lane * 8;          // lane-consecutive 16B frags
    const short* wrL = sW + WHALF + lane * 8;

    // double-buffered per-tile row fragments
    bf16x8 A0[2][KT], A1[2][KT];
    bf16x8 XB0[2][KT], XB1[2][KT];        // used when L2 (bf16 X rows)
    float4 XF0[2][KT][2], XF1[2][KT][2];  // used when !L2 (f32 X rows)

    auto LOAD = [&](bf16x8 (&A)[2][KT], bf16x8 (&XB)[2][KT],
                    float4 (&XF)[2][KT][2], int tile) {
        const int rowbase = tile * 128 + wv * 32;
#pragma unroll
        for (int st = 0; st < 2; ++st) {
            int r = rowbase + st * 16 + m;
            int rc = r < N_NODES ? r : N_NODES - 1;
            const unsigned short* ap = Ab + (size_t)rc * K + quad * 8;
#pragma unroll
            for (int kt = 0; kt < KT; ++kt)
                A[st][kt] = *(const bf16x8*)(ap + kt * 32);
            if constexpr (L2) {
                const unsigned short* xp = Xb + (size_t)rc * K + quad * 8;
#pragma unroll
                for (int kt = 0; kt < KT; ++kt)
                    XB[st][kt] = *(const bf16x8*)(xp + kt * 32);
            } else {
                const float* xp = Xf + (size_t)rc * K + quad * 8;
#pragma unroll
                for (int kt = 0; kt < KT; ++kt) {
                    XF[st][kt][0] = *(const float4*)(xp + kt * 32);
                    XF[st][kt][1] = *(const float4*)(xp + kt * 32 + 4);
                }
            }
        }
    };

    auto COMP = [&](bf16x8 (&A)[2][KT], bf16x8 (&XB)[2][KT],
                    float4 (&XF)[2][KT][2], int tile) {
        bf16x8 xR[2][KT];
        if constexpr (L2) {
#pragma unroll
            for (int st = 0; st < 2; ++st)
#pragma unroll
                for (int kt = 0; kt < KT; ++kt) xR[st][kt] = XB[st][kt];
        } else {
#pragma unroll
            for (int st = 0; st < 2; ++st)
#pragma unroll
                for (int kt = 0; kt < KT; ++kt) {
                    xR[st][kt][0] = (short)f2bf(XF[st][kt][0].x);
                    xR[st][kt][1] = (short)f2bf(XF[st][kt][0].y);
                    xR[st][kt][2] = (short)f2bf(XF[st][kt][0].z);
                    xR[st][kt][3] = (short)f2bf(XF[st][kt][0].w);
                    xR[st][kt][4] = (short)f2bf(XF[st][kt][1].x);
                    xR[st][kt][5] = (short)f2bf(XF[st][kt][1].y);
                    xR[st][kt][6] = (short)f2bf(XF[st][kt][1].z);
                    xR[st][kt][7] = (short)f2bf(XF[st][kt][1].w);
                }
        }
        f32x4 acc[2][8] = {};
#pragma unroll
        for (int kt = 0; kt < KT; ++kt) {
#pragma unroll
            for (int nt = 0; nt < 8; ++nt) {
                bf16x8 wl = *(const bf16x8*)(wlL + (nt * KT + kt) * 512);
#pragma unroll
                for (int st = 0; st < 2; ++st)
                    acc[st][nt] = __builtin_amdgcn_mfma_f32_16x16x32_bf16(
                        A[st][kt], wl, acc[st][nt], 0, 0, 0);
                bf16x8 wr = *(const bf16x8*)(wrL + (nt * KT + kt) * 512);
#pragma unroll
                for (int st = 0; st < 2; ++st)
                    acc[st][nt] = __builtin_amdgcn_mfma_f32_16x16x32_bf16(
                        xR[st][kt], wr, acc[st][nt], 0, 0, 0);
            }
        }
        // epilogue: C/D layout col = lane&15, row = quad*4 + reg
        const int rowbase = tile * 128 + wv * 32;
#pragma unroll
        for (int st = 0; st < 2; ++st) {
            const int orow = rowbase + st * 16 + quad * 4;
            float dg[4];
            if constexpr (L2) {
#pragma unroll
                for (int r = 0; r < 4; ++r) {
                    int rr = orow + r;
                    dg[r] = (rr < N_NODES) ? degf[rr] : 0.f;
                }
            }
#pragma unroll
            for (int nt = 0; nt < 8; ++nt) {
                int col = nt * 16 + m;
#pragma unroll
                for (int r = 0; r < 4; ++r) {
                    int rr = orow + r;
                    if (rr < N_NODES) {
                        float base = L2 ? fmaf(dg[r], ccol[nt], bcol[nt]) : bcol[nt];
                        float v = fmaxf(acc[st][nt][r] + base, 0.f);
                        if constexpr (L2) outF[(size_t)rr * 128 + col] = v;
                        else              outB[(size_t)rr * 128 + col] = f2bf(v);
                        stS[nt] += v;
                        stQ[nt] = fmaf(v, v, stQ[nt]);
                    }
                }
            }
        }
    };

    // ---- 2-stage software pipeline over the block's tiles ----
    int t = blockIdx.x;
    LOAD(A0, XB0, XF0, t);
    for (;;) {
        int tn = t + GGRID;
        if (tn < NT) {
            LOAD(A1, XB1, XF1, tn);
            COMP(A0, XB0, XF0, t);
            t = tn;
            tn = t + GGRID;
            if (tn < NT) {
                LOAD(A0, XB0, XF0, tn);
                COMP(A1, XB1, XF1, t);
                t = tn;
            } else {
                COMP(A1, XB1, XF1, t);
                break;
            }
        } else {
            COMP(A0, XB0, XF0, t);
            break;
        }
    }

    // ---- stats reduce once per block (overlay on dead weight LDS) ----
    float* sS = (float*)sW;
    float* sQ = ((float*)sW) + 128;
    __syncthreads();                      // all weight reads complete
    if (tid < 128) { sS[tid] = 0.f; sQ[tid] = 0.f; }
    __syncthreads();
#pragma unroll
    for (int nt = 0; nt < 8; ++nt) {
        atomicAdd(&sS[nt * 16 + m], stS[nt]);
        atomicAdd(&sQ[nt * 16 + m], stQ[nt]);
    }
    __syncthreads();
    const int rep = (blockIdx.x & 3) * 128;
    if (tid < 128) {
        atomicAdd(&gsum[rep + tid], sS[tid]);
        atomicAdd(&gsq[rep + tid],  sQ[tid]);
    }
}

// ---------------------------------------------------------------------------
// BN finalize: per-feature scale/shift (sums the 4 stats replicas).
// ---------------------------------------------------------------------------
__global__ void bn_finalize_kernel(
    const float* __restrict__ gsum, const float* __restrict__ gsq,
    const float* __restrict__ g, const float* __restrict__ be,
    float* __restrict__ scale, float* __restrict__ shift, float invN)
{
    int c = threadIdx.x;  // 128
    float s = gsum[c] + gsum[128 + c] + gsum[256 + c] + gsum[384 + c];
    float q = gsq[c]  + gsq[128 + c]  + gsq[256 + c]  + gsq[384 + c];
    float mean = s * invN;
    float var  = fmaxf(q * invN - mean * mean, 0.f);
    float sc   = g[c] * rsqrtf(var + BN_EPS);
    scale[c] = sc;
    shift[c] = be[c] - mean * sc;
}

// BN1 fold constants: c2 = shift1@W2l ; crb = shift1@W2r + b2
__global__ void bn_fold_kernel(
    const float* __restrict__ shift1, const float* __restrict__ W2l,
    const float* __restrict__ W2r, const float* __restrict__ b2,
    float* __restrict__ c2, float* __restrict__ crb)
{
    int col = threadIdx.x;  // 128
    float a = 0.f, r = 0.f;
    for (int k = 0; k < 128; ++k) {
        float s = shift1[k];
        a = fmaf(s, W2l[(size_t)k * 128 + col], a);
        r = fmaf(s, W2r[(size_t)k * 128 + col], r);
    }
    c2[col]  = a;
    crb[col] = r + b2[col];
}

// ---------------------------------------------------------------------------
// Final BN apply + ReLU (in place on d_out).
// ---------------------------------------------------------------------------
__global__ __launch_bounds__(256) void bn_apply_relu_kernel(
    float* __restrict__ h, const float* __restrict__ scale,
    const float* __restrict__ shift, int n4)
{
    int i = blockIdx.x * 256 + threadIdx.x;
    if (i >= n4) return;
    int cb = i & 31;
    float4 v  = ((float4*)h)[i];
    float4 sc = ((const float4*)scale)[cb];
    float4 sh = ((const float4*)shift)[cb];
    v.x = fmaxf(fmaf(v.x, sc.x, sh.x), 0.f);
    v.y = fmaxf(fmaf(v.y, sc.y, sh.y), 0.f);
    v.z = fmaxf(fmaf(v.z, sc.z, sh.z), 0.f);
    v.w = fmaxf(fmaf(v.w, sc.w, sh.w), 0.f);
    ((float4*)h)[i] = v;
}

extern "C" void kernel_launch(void* const* d_in, const int* in_sizes, int n_in,
                              void* d_out, int out_size, void* d_ws, size_t ws_size,
                              hipStream_t stream) {
    const float* x   = (const float*)d_in[0];
    const int*   ei  = (const int*)d_in[1];
    const float* W1l = (const float*)d_in[2];
    const float* b1  = (const float*)d_in[3];
    const float* W1r = (const float*)d_in[4];
    const float* g1  = (const float*)d_in[5];
    const float* be1 = (const float*)d_in[6];
    const float* W2l = (const float*)d_in[7];
    const float* b2  = (const float*)d_in[8];
    const float* W2r = (const float*)d_in[9];
    const float* g2  = (const float*)d_in[10];
    const float* be2 = (const float*)d_in[11];
    float* out = (float*)d_out;

    const int N = N_NODES, E = N_EDGES;
    const int NB1 = (N + 1023) / 1024;          // 196 scan blocks

    // Workspace layout (float units):
    float* ws     = (float*)d_ws;
    float* gsum1  = ws;          float* gsq1   = ws + 512;    // 4 replicas x 128
    float* gsum2  = ws + 1024;   float* gsq2   = ws + 1536;
    float* scale1 = ws + 2048;   float* shift1 = ws + 2176;
    float* scale2 = ws + 2304;   float* shift2 = ws + 2432;
    float* c2v    = ws + 2560;   float* crb    = ws + 2688;
    short* W1lp = (short*)(ws + 3072);                        // 4096 f
    short* W1rp = (short*)(ws + 3072 + 4096);                 // 4096 f
    short* W2lp = (short*)(ws + 3072 + 8192);                 // 8192 f
    short* W2rp = (short*)(ws + 3072 + 16384);                // 8192 f
    int*   deg    = (int*)(ws + 27648);                       // N
    int*   part   = deg + N;                                  // N
    int*   bsum   = part + N;                                 // 1024
    int*   rowptr = bsum + 1024;                              // N+1
    int*   bcursor= rowptr + (N + 1024);                      // 256
    float* degf   = (float*)(bcursor + N);                    // N
    int*   ssrc   = (int*)(degf + N);                         // E
    unsigned short* t1   = (unsigned short*)(ssrc + E);       // N*128 bf16
    unsigned short* aggb = t1 + (size_t)N * F_H;              // N*128 bf16
    unsigned* binned = (unsigned*)aggb;                       // E u32 (dead until gather1)

    // ---- Graph build + layer-1 weight pack ----
    hipMemsetAsync(ws, 0, 2048 * sizeof(float), stream);      // stats replicas
    hipMemsetAsync(deg, 0, (size_t)N * sizeof(int), stream);
    pack_weights_kernel<<<4, 256, 0, stream>>>(W1l, nullptr, W1lp, 2);
    pack_weights_kernel<<<4, 256, 0, stream>>>(W1r, nullptr, W1rp, 2);
    hist_kernel<<<(E + 255) / 256, 256, 0, stream>>>(ei, deg, E);
    scan1_kernel<<<NB1, 256, 0, stream>>>(deg, part, bsum, N);
    scan2_kernel<<<1, 256, 0, stream>>>(bsum, NB1);
    scan3_kernel<<<(N + 255) / 256, 256, 0, stream>>>(part, bsum, deg, rowptr,
                                                      bcursor, degf, N, E);
    bin_kernel<<<BINB, 256, 0, stream>>>(ei, bcursor, binned, E);
    scatter_kernel<<<NBUK, 256, 0, stream>>>(binned, rowptr, ssrc);

    // ---- Layer 1 ----
    gather1_kernel<<<N / 16, 256, 0, stream>>>(x, rowptr, ssrc, aggb);
    gemm_mfma_kernel<F_IN, false><<<GGRID, 256, 0, stream>>>(
        aggb, x, nullptr, (const bf16x8*)W1lp, (const bf16x8*)W1rp, b1,
        nullptr, nullptr, nullptr, t1, gsum1, gsq1);
    bn_finalize_kernel<<<1, 128, 0, stream>>>(gsum1, gsq1, g1, be1,
                                              scale1, shift1, 1.f / N);

    // ---- Layer 2 (BN1 folded: scale1 into weights, shift1 into c2/crb) ----
    pack_weights_kernel<<<8, 256, 0, stream>>>(W2l, scale1, W2lp, 4);
    pack_weights_kernel<<<8, 256, 0, stream>>>(W2r, scale1, W2rp, 4);
    bn_fold_kernel<<<1, 128, 0, stream>>>(shift1, W2l, W2r, b2, c2v, crb);
    gather2_kernel<<<N / 16, 256, 0, stream>>>(t1, rowptr, ssrc, aggb);
    gemm_mfma_kernel<F_H, true><<<GGRID, 256, 0, stream>>>(
        aggb, nullptr, t1, (const bf16x8*)W2lp, (const bf16x8*)W2rp, crb,
        c2v, degf, out, nullptr, gsum2, gsq2);
    bn_finalize_kernel<<<1, 128, 0, stream>>>(gsum2, gsq2, g2, be2,
                                              scale2, shift2, 1.f / N);
    bn_apply_relu_kernel<<<(N * F_H / 4 + 255) / 256, 256, 0, stream>>>(
        out, scale2, shift2, N * F_H / 4);
}

// Round 4
// 530.350 us; speedup vs baseline: 1.0369x; 1.0369x over previous
//
#include <hip/hip_runtime.h>

#define N_NODES 200000
#define N_EDGES 1200000
#define F_IN    64
#define F_H     128
#define BN_EPS  1e-5f
#define NBUK    196          // ceil(N/1024) dst-buckets of 1024 nodes
#define BINB    293          // ceil(E/4096) bin blocks

typedef short bf16x8 __attribute__((ext_vector_type(8)));   // 8 bf16 in 4 VGPRs
typedef float f32x4  __attribute__((ext_vector_type(4)));
typedef unsigned short us4 __attribute__((ext_vector_type(4)));

__device__ __forceinline__ unsigned short f2bf(float f) {
    union { float f; unsigned u; } v; v.f = f;
    unsigned r = (v.u + 0x7FFFu + ((v.u >> 16) & 1u)) >> 16;  // RNE
    return (unsigned short)r;
}
__device__ __forceinline__ float bf2f(unsigned short b) {
    union { unsigned u; float f; } v; v.u = ((unsigned)b) << 16;
    return v.f;
}

// ---------------------------------------------------------------------------
// Weight pack into bf16 MFMA B-fragment order for mfma_f32_16x16x32_bf16.
// ---------------------------------------------------------------------------
__global__ void pack_weights_kernel(const float* __restrict__ W,
                                    const float* __restrict__ kscale,
                                    short* __restrict__ P, int KT)
{
    int t = blockIdx.x * 256 + threadIdx.x;            // over 8*KT*64
    if (t >= 8 * KT * 64) return;
    int lane = t & 63;
    int kt   = (t >> 6) % KT;
    int nt   = t / (64 * KT);
    int k0   = kt * 32 + (lane >> 4) * 8;
    int n    = nt * 16 + (lane & 15);
#pragma unroll
    for (int j = 0; j < 8; ++j) {
        float w = W[(size_t)(k0 + j) * 128 + n];
        if (kscale) w *= kscale[k0 + j];
        P[(size_t)t * 8 + j] = (short)f2bf(w);
    }
}

// ---------------------------------------------------------------------------
// CSR build: histogram -> 2-level exclusive scan over deg -> bucketed fill
// ---------------------------------------------------------------------------
__global__ __launch_bounds__(256) void hist_kernel(const int* __restrict__ ei,
                                                   int* __restrict__ deg, int E)
{
    int e = blockIdx.x * 256 + threadIdx.x;
    if (e < E) atomicAdd(&deg[ei[E + e]], 1);
}

__global__ __launch_bounds__(256) void scan1_kernel(const int* __restrict__ deg,
        int* __restrict__ part, int* __restrict__ bsum, int n)
{
    __shared__ int s[256];
    int t = threadIdx.x;
    int base = blockIdx.x * 1024 + t * 4;
    int v[4];
#pragma unroll
    for (int j = 0; j < 4; ++j) v[j] = (base + j < n) ? deg[base + j] : 0;
    int tsum = v[0] + v[1] + v[2] + v[3];
    s[t] = tsum;
    __syncthreads();
    for (int off = 1; off < 256; off <<= 1) {
        int xv = (t >= off) ? s[t - off] : 0;
        __syncthreads();
        s[t] += xv;
        __syncthreads();
    }
    int excl = s[t] - tsum;
#pragma unroll
    for (int j = 0; j < 4; ++j) {
        if (base + j < n) part[base + j] = excl;
        excl += v[j];
    }
    if (t == 255) bsum[blockIdx.x] = s[255];
}

__global__ void scan2_kernel(int* __restrict__ bsum, int nb)
{
    __shared__ int s[256];
    int t = threadIdx.x;
    int v = (t < nb) ? bsum[t] : 0;
    s[t] = v;
    __syncthreads();
    for (int off = 1; off < 256; off <<= 1) {
        int xv = (t >= off) ? s[t - off] : 0;
        __syncthreads();
        s[t] += xv;
        __syncthreads();
    }
    if (t < nb) bsum[t] = s[t] - v;   // exclusive
}

__global__ __launch_bounds__(256) void scan3_kernel(
    const int* __restrict__ part, const int* __restrict__ bsum,
    const int* __restrict__ deg, int* __restrict__ rowptr,
    int* __restrict__ bcursor, float* __restrict__ degf, int n, int E)
{
    int i = blockIdx.x * 256 + threadIdx.x;
    if (i == 0) rowptr[n] = E;
    if (i >= n) return;
    int r = part[i] + bsum[i >> 10];
    rowptr[i] = r;
    if ((i & 1023) == 0) bcursor[i >> 10] = r;   // bucket segment base
    degf[i]   = (float)deg[i];
}

// ---------------------------------------------------------------------------
// bin_kernel: LDS multi-split of edges into 196 contiguous-dst buckets.
// ---------------------------------------------------------------------------
__global__ __launch_bounds__(256) void bin_kernel(
    const int* __restrict__ ei, int* __restrict__ bcursor,
    unsigned* __restrict__ binned, int E)
{
    __shared__ int lcnt[256];
    __shared__ int lbase[256];
    __shared__ int gbase[256];
    __shared__ int sc[256];
    __shared__ unsigned stage[4096];
    __shared__ unsigned char stgb[4096];
    const int tid  = threadIdx.x;
    const int base = blockIdx.x * 4096;
    lcnt[tid] = 0;
    __syncthreads();

    unsigned val[16]; short lp[16]; unsigned char bk[16];
#pragma unroll
    for (int i = 0; i < 16; ++i) {
        int e = base + i * 256 + tid;
        if (e < E) {
            int s = ei[e], d = ei[E + e];
            int b = d >> 10;
            val[i] = ((unsigned)s << 10) | (unsigned)(d & 1023);
            bk[i]  = (unsigned char)b;
            lp[i]  = (short)atomicAdd(&lcnt[b], 1);
        } else lp[i] = -1;
    }
    __syncthreads();

    // exclusive scan of per-bucket counts + global range reservation
    int c = lcnt[tid];
    sc[tid] = c;
    __syncthreads();
    for (int off = 1; off < 256; off <<= 1) {
        int v = (tid >= off) ? sc[tid - off] : 0;
        __syncthreads();
        sc[tid] += v;
        __syncthreads();
    }
    lbase[tid] = sc[tid] - c;
    if (c) gbase[tid] = atomicAdd(&bcursor[tid], c);
    __syncthreads();
    const int total = sc[255];

    // bucket-sorted stage in LDS
#pragma unroll
    for (int i = 0; i < 16; ++i) {
        if (lp[i] >= 0) {
            int p = lbase[bk[i]] + lp[i];
            stage[p] = val[i];
            stgb[p]  = bk[i];
        }
    }
    __syncthreads();

    // write out: consecutive p within a bucket -> consecutive global addrs
    for (int p = tid; p < total; p += 256) {
        int b = stgb[p];
        binned[gbase[b] + (p - lbase[b])] = stage[p];
    }
}

// ---------------------------------------------------------------------------
// scatter_kernel: one block per bucket; LDS cursors; writes stay in-bucket.
// ---------------------------------------------------------------------------
__global__ __launch_bounds__(256) void scatter_kernel(
    const unsigned* __restrict__ binned, const int* __restrict__ rowptr,
    int* __restrict__ ssrc)
{
    __shared__ int cur[1024];
    const int b    = blockIdx.x;
    const int tid  = threadIdx.x;
    const int dbase = b << 10;
    const int dmax  = min(1024, N_NODES - dbase);
    for (int j = tid; j < dmax; j += 256) cur[j] = rowptr[dbase + j];
    __syncthreads();
    const int s0 = rowptr[dbase];
    const int s1 = rowptr[dbase + dmax];
    for (int e = s0 + tid; e < s1; e += 256) {
        unsigned v = binned[e];
        int pos = atomicAdd(&cur[v & 1023u], 1);
        ssrc[pos] = (int)(v >> 10);
    }
}

// ---------------------------------------------------------------------------
// Fused SAGE layer (R4): gather + GEMM + BN-stats in ONE kernel.
// Rationale: R0/R2/R3 gemm variants all pinned at ~100-108 us regardless of
// weight path / occupancy / pipelining — the shared cost was the aggb HBM
// round trip (gather writes 51 MB, gemm re-reads it) plus two separate
// latency-bound dispatch ramps per layer.
//
// Block = 128 rows. Phase 1: each wave aggregates neighbors for 32 rows
// (4 rows/pass x 8 passes, 8-deep neighbor batching) straight into a padded
// LDS A-tile (row stride K*2+16 B -> the 16-lane row-strided fragment reads
// are 2 lanes/bank = conflict-free). Root-X loads are issued BEFORE the
// gather so their HBM latency hides under gather work. Phase 2: A-frags
// from LDS, weights from global (L2-hot; proven non-bottleneck R0 vs R2),
// MFMA K-loop, fused bias/ReLU/deg-fold epilogue + BN stats.
// ---------------------------------------------------------------------------
template<int K, bool L2>
__global__ __launch_bounds__(256, 3) void fused_sage_kernel(
    const float* __restrict__ xgF,           // L1: x (f32 gather src + root)
    const unsigned short* __restrict__ xgB,  // L2: t1 (bf16 gather src + root)
    const int* __restrict__ rowptr, const int* __restrict__ ssrc,
    const bf16x8* __restrict__ Wlp, const bf16x8* __restrict__ Wrp,
    const float* __restrict__ bias,
    const float* __restrict__ c2, const float* __restrict__ degf,
    float* __restrict__ outF, unsigned short* __restrict__ outB,
    float* __restrict__ gsum, float* __restrict__ gsq)
{
    constexpr int KT = K / 32;
    constexpr int RB = K * 2 + 16;            // padded LDS row stride (bytes)
    __shared__ unsigned char sA[128 * RB];
    __shared__ float sS[128];
    __shared__ float sQ[128];

    const int tid  = threadIdx.x;
    const int lane = tid & 63;
    const int wv   = tid >> 6;
    const int m    = lane & 15;
    const int quad = lane >> 4;
    const int li   = lane & 15;
    const int sub  = lane >> 4;               // 0..3 (4 rows per gather pass)
    const int rowbase = blockIdx.x * 128 + wv * 32;

    if (tid < 128) { sS[tid] = 0.f; sQ[tid] = 0.f; }

    // ---- root-X prefetch: issued first, lands during the gather phase ----
    int rc[2];
#pragma unroll
    for (int st = 0; st < 2; ++st) {
        int r = rowbase + st * 16 + m;
        rc[st] = r < N_NODES ? r : N_NODES - 1;
    }
    bf16x8 xReg[2][KT];
    float4 xr[2][KT][2];
    if constexpr (L2) {
#pragma unroll
        for (int st = 0; st < 2; ++st) {
            const unsigned short* xp = xgB + (size_t)rc[st] * K + quad * 8;
#pragma unroll
            for (int kt = 0; kt < KT; ++kt)
                xReg[st][kt] = *(const bf16x8*)(xp + kt * 32);
        }
    } else {
#pragma unroll
        for (int st = 0; st < 2; ++st) {
            const float* xp = xgF + (size_t)rc[st] * K + quad * 8;
#pragma unroll
            for (int kt = 0; kt < KT; ++kt) {
                xr[st][kt][0] = *(const float4*)(xp + kt * 32);
                xr[st][kt][1] = *(const float4*)(xp + kt * 32 + 4);
            }
        }
    }

    // ---- gather phase: aggregate neighbors into the LDS A-tile ----
    for (int g = 0; g < 8; ++g) {
        const int lrow = wv * 32 + g * 4 + sub;
        const int row  = blockIdx.x * 128 + lrow;
        const bool vr  = row < N_NODES;
        const int b = vr ? rowptr[row]     : 0;
        const int e = vr ? rowptr[row + 1] : 0;
        if constexpr (L2) {
            float acc[8] = {};
            int s[8];
#pragma unroll
            for (int q = 0; q < 8; ++q) s[q] = (b + q < e) ? ssrc[b + q] : 0;
            for (int j = b; j < e; j += 8) {
                int nn[8];
                const int jn = j + 8;
#pragma unroll
                for (int q = 0; q < 8; ++q) nn[q] = (jn + q < e) ? ssrc[jn + q] : 0;
                bf16x8 v[8];
#pragma unroll
                for (int q = 0; q < 8; ++q)
                    v[q] = *(const bf16x8*)(xgB + (size_t)s[q] * K + li * 8);
#pragma unroll
                for (int q = 0; q < 8; ++q) {
                    float w = (j + q < e) ? 1.f : 0.f;
#pragma unroll
                    for (int k = 0; k < 8; ++k)
                        acc[k] = fmaf(bf2f((unsigned short)v[q][k]), w, acc[k]);
                }
#pragma unroll
                for (int q = 0; q < 8; ++q) s[q] = nn[q];
            }
            bf16x8 o;
#pragma unroll
            for (int k = 0; k < 8; ++k) o[k] = (short)f2bf(acc[k]);
            *(bf16x8*)(sA + lrow * RB + li * 16) = o;
        } else {
            float4 a4 = {0.f, 0.f, 0.f, 0.f};
            int s[8];
#pragma unroll
            for (int q = 0; q < 8; ++q) s[q] = (b + q < e) ? ssrc[b + q] : 0;
            for (int j = b; j < e; j += 8) {
                int nn[8];
                const int jn = j + 8;
#pragma unroll
                for (int q = 0; q < 8; ++q) nn[q] = (jn + q < e) ? ssrc[jn + q] : 0;
                float4 v[8];
#pragma unroll
                for (int q = 0; q < 8; ++q)
                    v[q] = ((const float4*)(xgF + (size_t)s[q] * K))[li];
#pragma unroll
                for (int q = 0; q < 8; ++q) {
                    float w = (j + q < e) ? 1.f : 0.f;
                    a4.x = fmaf(v[q].x, w, a4.x);
                    a4.y = fmaf(v[q].y, w, a4.y);
                    a4.z = fmaf(v[q].z, w, a4.z);
                    a4.w = fmaf(v[q].w, w, a4.w);
                }
#pragma unroll
                for (int q = 0; q < 8; ++q) s[q] = nn[q];
            }
            us4 o;
            o.x = f2bf(a4.x); o.y = f2bf(a4.y); o.z = f2bf(a4.z); o.w = f2bf(a4.w);
            *(us4*)(sA + lrow * RB + li * 8) = o;
        }
    }

    // L1: convert prefetched f32 root rows to bf16 fragments
    if constexpr (!L2) {
#pragma unroll
        for (int st = 0; st < 2; ++st)
#pragma unroll
            for (int kt = 0; kt < KT; ++kt) {
                xReg[st][kt][0] = (short)f2bf(xr[st][kt][0].x);
                xReg[st][kt][1] = (short)f2bf(xr[st][kt][0].y);
                xReg[st][kt][2] = (short)f2bf(xr[st][kt][0].z);
                xReg[st][kt][3] = (short)f2bf(xr[st][kt][0].w);
                xReg[st][kt][4] = (short)f2bf(xr[st][kt][1].x);
                xReg[st][kt][5] = (short)f2bf(xr[st][kt][1].y);
                xReg[st][kt][6] = (short)f2bf(xr[st][kt][1].z);
                xReg[st][kt][7] = (short)f2bf(xr[st][kt][1].w);
            }
    }

    // per-nt epilogue constants (col = nt*16 + m)
    float bcol[8], ccol[8];
#pragma unroll
    for (int nt = 0; nt < 8; ++nt) {
        bcol[nt] = bias[nt * 16 + m];
        if constexpr (L2) ccol[nt] = c2[nt * 16 + m];
    }

    __syncthreads();   // A-tile complete

    // ---- A fragments from LDS (padded stride: conflict-free) ----
    bf16x8 aReg[2][KT];
#pragma unroll
    for (int st = 0; st < 2; ++st) {
        const unsigned char* ap = sA + (wv * 32 + st * 16 + m) * RB + quad * 16;
#pragma unroll
        for (int kt = 0; kt < KT; ++kt)
            aReg[st][kt] = *(const bf16x8*)(ap + kt * 64);
    }

    // ---- K loop: weights from global (L2-hot) + MFMA ----
    f32x4 acc[2][8] = {};
#pragma unroll
    for (int kt = 0; kt < KT; ++kt) {
#pragma unroll
        for (int nt = 0; nt < 8; ++nt) {
            bf16x8 wl = Wlp[(nt * KT + kt) * 64 + lane];
#pragma unroll
            for (int st = 0; st < 2; ++st)
                acc[st][nt] = __builtin_amdgcn_mfma_f32_16x16x32_bf16(
                    aReg[st][kt], wl, acc[st][nt], 0, 0, 0);
            bf16x8 wr = Wrp[(nt * KT + kt) * 64 + lane];
#pragma unroll
            for (int st = 0; st < 2; ++st)
                acc[st][nt] = __builtin_amdgcn_mfma_f32_16x16x32_bf16(
                    xReg[st][kt], wr, acc[st][nt], 0, 0, 0);
        }
    }

    // ---- epilogue: C/D layout col = lane&15, row = quad*4 + reg ----
    float stS[8] = {}, stQ[8] = {};
#pragma unroll
    for (int st = 0; st < 2; ++st) {
        const int orow = rowbase + st * 16 + quad * 4;
        float dg[4];
        if constexpr (L2) {
#pragma unroll
            for (int r = 0; r < 4; ++r) {
                int rr = orow + r;
                dg[r] = (rr < N_NODES) ? degf[rr] : 0.f;
            }
        }
#pragma unroll
        for (int nt = 0; nt < 8; ++nt) {
            int col = nt * 16 + m;
#pragma unroll
            for (int r = 0; r < 4; ++r) {
                int rr = orow + r;
                if (rr < N_NODES) {
                    float base = L2 ? fmaf(dg[r], ccol[nt], bcol[nt]) : bcol[nt];
                    float v = fmaxf(acc[st][nt][r] + base, 0.f);
                    if constexpr (L2) outF[(size_t)rr * 128 + col] = v;
                    else              outB[(size_t)rr * 128 + col] = f2bf(v);
                    stS[nt] += v;
                    stQ[nt] = fmaf(v, v, stQ[nt]);
                }
            }
        }
    }

    // ---- stats reduce: registers -> LDS -> global replica ----
#pragma unroll
    for (int nt = 0; nt < 8; ++nt) {
        atomicAdd(&sS[nt * 16 + m], stS[nt]);
        atomicAdd(&sQ[nt * 16 + m], stQ[nt]);
    }
    __syncthreads();
    const int rep = (blockIdx.x & 3) * 128;
    if (tid < 128) {
        atomicAdd(&gsum[rep + tid], sS[tid]);
        atomicAdd(&gsq[rep + tid],  sQ[tid]);
    }
}

// ---------------------------------------------------------------------------
// BN finalize: per-feature scale/shift (sums the 4 stats replicas).
// ---------------------------------------------------------------------------
__global__ void bn_finalize_kernel(
    const float* __restrict__ gsum, const float* __restrict__ gsq,
    const float* __restrict__ g, const float* __restrict__ be,
    float* __restrict__ scale, float* __restrict__ shift, float invN)
{
    int c = threadIdx.x;  // 128
    float s = gsum[c] + gsum[128 + c] + gsum[256 + c] + gsum[384 + c];
    float q = gsq[c]  + gsq[128 + c]  + gsq[256 + c]  + gsq[384 + c];
    float mean = s * invN;
    float var  = fmaxf(q * invN - mean * mean, 0.f);
    float sc   = g[c] * rsqrtf(var + BN_EPS);
    scale[c] = sc;
    shift[c] = be[c] - mean * sc;
}

// BN1 fold constants: c2 = shift1@W2l ; crb = shift1@W2r + b2
__global__ void bn_fold_kernel(
    const float* __restrict__ shift1, const float* __restrict__ W2l,
    const float* __restrict__ W2r, const float* __restrict__ b2,
    float* __restrict__ c2, float* __restrict__ crb)
{
    int col = threadIdx.x;  // 128
    float a = 0.f, r = 0.f;
    for (int k = 0; k < 128; ++k) {
        float s = shift1[k];
        a = fmaf(s, W2l[(size_t)k * 128 + col], a);
        r = fmaf(s, W2r[(size_t)k * 128 + col], r);
    }
    c2[col]  = a;
    crb[col] = r + b2[col];
}

// ---------------------------------------------------------------------------
// Final BN apply + ReLU (in place on d_out).
// ---------------------------------------------------------------------------
__global__ __launch_bounds__(256) void bn_apply_relu_kernel(
    float* __restrict__ h, const float* __restrict__ scale,
    const float* __restrict__ shift, int n4)
{
    int i = blockIdx.x * 256 + threadIdx.x;
    if (i >= n4) return;
    int cb = i & 31;
    float4 v  = ((float4*)h)[i];
    float4 sc = ((const float4*)scale)[cb];
    float4 sh = ((const float4*)shift)[cb];
    v.x = fmaxf(fmaf(v.x, sc.x, sh.x), 0.f);
    v.y = fmaxf(fmaf(v.y, sc.y, sh.y), 0.f);
    v.z = fmaxf(fmaf(v.z, sc.z, sh.z), 0.f);
    v.w = fmaxf(fmaf(v.w, sc.w, sh.w), 0.f);
    ((float4*)h)[i] = v;
}

extern "C" void kernel_launch(void* const* d_in, const int* in_sizes, int n_in,
                              void* d_out, int out_size, void* d_ws, size_t ws_size,
                              hipStream_t stream) {
    const float* x   = (const float*)d_in[0];
    const int*   ei  = (const int*)d_in[1];
    const float* W1l = (const float*)d_in[2];
    const float* b1  = (const float*)d_in[3];
    const float* W1r = (const float*)d_in[4];
    const float* g1  = (const float*)d_in[5];
    const float* be1 = (const float*)d_in[6];
    const float* W2l = (const float*)d_in[7];
    const float* b2  = (const float*)d_in[8];
    const float* W2r = (const float*)d_in[9];
    const float* g2  = (const float*)d_in[10];
    const float* be2 = (const float*)d_in[11];
    float* out = (float*)d_out;

    const int N = N_NODES, E = N_EDGES;
    const int NB1 = (N + 1023) / 1024;          // 196 scan blocks
    const int nT  = (N + 127) / 128;            // 1563 fused blocks

    // Workspace layout (float units):
    float* ws     = (float*)d_ws;
    float* gsum1  = ws;          float* gsq1   = ws + 512;    // 4 replicas x 128
    float* gsum2  = ws + 1024;   float* gsq2   = ws + 1536;
    float* scale1 = ws + 2048;   float* shift1 = ws + 2176;
    float* scale2 = ws + 2304;   float* shift2 = ws + 2432;
    float* c2v    = ws + 2560;   float* crb    = ws + 2688;
    short* W1lp = (short*)(ws + 3072);                        // 4096 f
    short* W1rp = (short*)(ws + 3072 + 4096);                 // 4096 f
    short* W2lp = (short*)(ws + 3072 + 8192);                 // 8192 f
    short* W2rp = (short*)(ws + 3072 + 16384);                // 8192 f
    int*   deg    = (int*)(ws + 27648);                       // N
    int*   part   = deg + N;                                  // N
    int*   bsum   = part + N;                                 // 1024
    int*   rowptr = bsum + 1024;                              // N+1
    int*   bcursor= rowptr + (N + 1024);                      // 256
    float* degf   = (float*)(bcursor + N);                    // N
    int*   ssrc   = (int*)(degf + N);                         // E
    unsigned short* t1   = (unsigned short*)(ssrc + E);       // N*128 bf16
    unsigned short* aggb = t1 + (size_t)N * F_H;              // (dead; binned lives here)
    unsigned* binned = (unsigned*)aggb;                       // E u32

    // ---- Graph build + layer-1 weight pack ----
    hipMemsetAsync(ws, 0, 2048 * sizeof(float), stream);      // stats replicas
    hipMemsetAsync(deg, 0, (size_t)N * sizeof(int), stream);
    pack_weights_kernel<<<4, 256, 0, stream>>>(W1l, nullptr, W1lp, 2);
    pack_weights_kernel<<<4, 256, 0, stream>>>(W1r, nullptr, W1rp, 2);
    hist_kernel<<<(E + 255) / 256, 256, 0, stream>>>(ei, deg, E);
    scan1_kernel<<<NB1, 256, 0, stream>>>(deg, part, bsum, N);
    scan2_kernel<<<1, 256, 0, stream>>>(bsum, NB1);
    scan3_kernel<<<(N + 255) / 256, 256, 0, stream>>>(part, bsum, deg, rowptr,
                                                      bcursor, degf, N, E);
    bin_kernel<<<BINB, 256, 0, stream>>>(ei, bcursor, binned, E);
    scatter_kernel<<<NBUK, 256, 0, stream>>>(binned, rowptr, ssrc);

    // ---- Layer 1 (fused gather + GEMM + stats) ----
    fused_sage_kernel<F_IN, false><<<nT, 256, 0, stream>>>(
        x, nullptr, rowptr, ssrc,
        (const bf16x8*)W1lp, (const bf16x8*)W1rp, b1,
        nullptr, nullptr, nullptr, t1, gsum1, gsq1);
    bn_finalize_kernel<<<1, 128, 0, stream>>>(gsum1, gsq1, g1, be1,
                                              scale1, shift1, 1.f / N);

    // ---- Layer 2 (BN1 folded: scale1 into weights, shift1 into c2/crb) ----
    pack_weights_kernel<<<8, 256, 0, stream>>>(W2l, scale1, W2lp, 4);
    pack_weights_kernel<<<8, 256, 0, stream>>>(W2r, scale1, W2rp, 4);
    bn_fold_kernel<<<1, 128, 0, stream>>>(shift1, W2l, W2r, b2, c2v, crb);
    fused_sage_kernel<F_H, true><<<nT, 256, 0, stream>>>(
        nullptr, t1, rowptr, ssrc,
        (const bf16x8*)W2lp, (const bf16x8*)W2rp, crb,
        c2v, degf, out, nullptr, gsum2, gsq2);
    bn_finalize_kernel<<<1, 128, 0, stream>>>(gsum2, gsq2, g2, be2,
                                              scale2, shift2, 1.f / N);
    bn_apply_relu_kernel<<<(N * F_H / 4 + 255) / 256, 256, 0, stream>>>(
        out, scale2, shift2, N * F_H / 4);
}

// Round 5
// 525.476 us; speedup vs baseline: 1.0465x; 1.0093x over previous
//
#include <hip/hip_runtime.h>

#define N_NODES 200000
#define N_EDGES 1200000
#define F_IN    64
#define F_H     128
#define BN_EPS  1e-5f
#define NBUK    196          // ceil(N/1024) dst-buckets of 1024 nodes
#define BINB    293          // ceil(E/4096) bin blocks

typedef short bf16x8 __attribute__((ext_vector_type(8)));   // 8 bf16 in 4 VGPRs
typedef float f32x4  __attribute__((ext_vector_type(4)));
typedef unsigned short us4 __attribute__((ext_vector_type(4)));

__device__ __forceinline__ unsigned short f2bf(float f) {
    union { float f; unsigned u; } v; v.f = f;
    unsigned r = (v.u + 0x7FFFu + ((v.u >> 16) & 1u)) >> 16;  // RNE
    return (unsigned short)r;
}
__device__ __forceinline__ float bf2f(unsigned short b) {
    union { unsigned u; float f; } v; v.u = ((unsigned)b) << 16;
    return v.f;
}

// ---------------------------------------------------------------------------
// Weight pack into bf16 MFMA B-fragment order for mfma_f32_16x16x32_bf16.
// ---------------------------------------------------------------------------
__global__ void pack_weights_kernel(const float* __restrict__ W,
                                    const float* __restrict__ kscale,
                                    short* __restrict__ P, int KT)
{
    int t = blockIdx.x * 256 + threadIdx.x;            // over 8*KT*64
    if (t >= 8 * KT * 64) return;
    int lane = t & 63;
    int kt   = (t >> 6) % KT;
    int nt   = t / (64 * KT);
    int k0   = kt * 32 + (lane >> 4) * 8;
    int n    = nt * 16 + (lane & 15);
#pragma unroll
    for (int j = 0; j < 8; ++j) {
        float w = W[(size_t)(k0 + j) * 128 + n];
        if (kscale) w *= kscale[k0 + j];
        P[(size_t)t * 8 + j] = (short)f2bf(w);
    }
}

// ---------------------------------------------------------------------------
// CSR build: histogram -> 2-level exclusive scan over deg -> bucketed fill
// ---------------------------------------------------------------------------
__global__ __launch_bounds__(256) void hist_kernel(const int* __restrict__ ei,
                                                   int* __restrict__ deg, int E)
{
    int e = blockIdx.x * 256 + threadIdx.x;
    if (e < E) atomicAdd(&deg[ei[E + e]], 1);
}

__global__ __launch_bounds__(256) void scan1_kernel(const int* __restrict__ deg,
        int* __restrict__ part, int* __restrict__ bsum, int n)
{
    __shared__ int s[256];
    int t = threadIdx.x;
    int base = blockIdx.x * 1024 + t * 4;
    int v[4];
#pragma unroll
    for (int j = 0; j < 4; ++j) v[j] = (base + j < n) ? deg[base + j] : 0;
    int tsum = v[0] + v[1] + v[2] + v[3];
    s[t] = tsum;
    __syncthreads();
    for (int off = 1; off < 256; off <<= 1) {
        int xv = (t >= off) ? s[t - off] : 0;
        __syncthreads();
        s[t] += xv;
        __syncthreads();
    }
    int excl = s[t] - tsum;
#pragma unroll
    for (int j = 0; j < 4; ++j) {
        if (base + j < n) part[base + j] = excl;
        excl += v[j];
    }
    if (t == 255) bsum[blockIdx.x] = s[255];
}

__global__ void scan2_kernel(int* __restrict__ bsum, int nb)
{
    __shared__ int s[256];
    int t = threadIdx.x;
    int v = (t < nb) ? bsum[t] : 0;
    s[t] = v;
    __syncthreads();
    for (int off = 1; off < 256; off <<= 1) {
        int xv = (t >= off) ? s[t - off] : 0;
        __syncthreads();
        s[t] += xv;
        __syncthreads();
    }
    if (t < nb) bsum[t] = s[t] - v;   // exclusive
}

__global__ __launch_bounds__(256) void scan3_kernel(
    const int* __restrict__ part, const int* __restrict__ bsum,
    const int* __restrict__ deg, int* __restrict__ rowptr,
    int* __restrict__ bcursor, float* __restrict__ degf, int n, int E)
{
    int i = blockIdx.x * 256 + threadIdx.x;
    if (i == 0) rowptr[n] = E;
    if (i >= n) return;
    int r = part[i] + bsum[i >> 10];
    rowptr[i] = r;
    if ((i & 1023) == 0) bcursor[i >> 10] = r;   // bucket segment base
    degf[i]   = (float)deg[i];
}

// ---------------------------------------------------------------------------
// bin_kernel: LDS multi-split of edges into 196 contiguous-dst buckets.
// ---------------------------------------------------------------------------
__global__ __launch_bounds__(256) void bin_kernel(
    const int* __restrict__ ei, int* __restrict__ bcursor,
    unsigned* __restrict__ binned, int E)
{
    __shared__ int lcnt[256];
    __shared__ int lbase[256];
    __shared__ int gbase[256];
    __shared__ int sc[256];
    __shared__ unsigned stage[4096];
    __shared__ unsigned char stgb[4096];
    const int tid  = threadIdx.x;
    const int base = blockIdx.x * 4096;
    lcnt[tid] = 0;
    __syncthreads();

    unsigned val[16]; short lp[16]; unsigned char bk[16];
#pragma unroll
    for (int i = 0; i < 16; ++i) {
        int e = base + i * 256 + tid;
        if (e < E) {
            int s = ei[e], d = ei[E + e];
            int b = d >> 10;
            val[i] = ((unsigned)s << 10) | (unsigned)(d & 1023);
            bk[i]  = (unsigned char)b;
            lp[i]  = (short)atomicAdd(&lcnt[b], 1);
        } else lp[i] = -1;
    }
    __syncthreads();

    // exclusive scan of per-bucket counts + global range reservation
    int c = lcnt[tid];
    sc[tid] = c;
    __syncthreads();
    for (int off = 1; off < 256; off <<= 1) {
        int v = (tid >= off) ? sc[tid - off] : 0;
        __syncthreads();
        sc[tid] += v;
        __syncthreads();
    }
    lbase[tid] = sc[tid] - c;
    if (c) gbase[tid] = atomicAdd(&bcursor[tid], c);
    __syncthreads();
    const int total = sc[255];

    // bucket-sorted stage in LDS
#pragma unroll
    for (int i = 0; i < 16; ++i) {
        if (lp[i] >= 0) {
            int p = lbase[bk[i]] + lp[i];
            stage[p] = val[i];
            stgb[p]  = bk[i];
        }
    }
    __syncthreads();

    // write out: consecutive p within a bucket -> consecutive global addrs
    for (int p = tid; p < total; p += 256) {
        int b = stgb[p];
        binned[gbase[b] + (p - lbase[b])] = stage[p];
    }
}

// ---------------------------------------------------------------------------
// scatter_kernel: one block per bucket; LDS cursors; writes stay in-bucket.
// ---------------------------------------------------------------------------
__global__ __launch_bounds__(256) void scatter_kernel(
    const unsigned* __restrict__ binned, const int* __restrict__ rowptr,
    int* __restrict__ ssrc)
{
    __shared__ int cur[1024];
    const int b    = blockIdx.x;
    const int tid  = threadIdx.x;
    const int dbase = b << 10;
    const int dmax  = min(1024, N_NODES - dbase);
    for (int j = tid; j < dmax; j += 256) cur[j] = rowptr[dbase + j];
    __syncthreads();
    const int s0 = rowptr[dbase];
    const int s1 = rowptr[dbase + dmax];
    for (int e = s0 + tid; e < s1; e += 256) {
        unsigned v = binned[e];
        int pos = atomicAdd(&cur[v & 1023u], 1);
        ssrc[pos] = (int)(v >> 10);
    }
}

// ---------------------------------------------------------------------------
// Fused SAGE layer (R5): gather + GEMM + BN-stats in ONE kernel.
// R5 gather restructure: R4's per-pass chain (rowptr -> ssrc -> feature
// rows, ~24 dependent latencies/wave) is pipelined away:
//  - the wave's 33 rowptr entries come from ONE coalesced load + shfl
//    broadcast (no LDS, no barrier, hop 1 gone),
//  - pass g+1's ssrc indices are prefetched WHILE pass g's feature loads
//    are in flight (hop 2 overlapped),
// so steady-state cost per pass is a single overlapped feature-load
// latency. Tail (deg>8, ~15% of rows) keeps the old batched loop.
// ---------------------------------------------------------------------------
template<int K, bool L2>
__global__ __launch_bounds__(256, 2) void fused_sage_kernel(
    const float* __restrict__ xgF,           // L1: x (f32 gather src + root)
    const unsigned short* __restrict__ xgB,  // L2: t1 (bf16 gather src + root)
    const int* __restrict__ rowptr, const int* __restrict__ ssrc,
    const bf16x8* __restrict__ Wlp, const bf16x8* __restrict__ Wrp,
    const float* __restrict__ bias,
    const float* __restrict__ c2, const float* __restrict__ degf,
    float* __restrict__ outF, unsigned short* __restrict__ outB,
    float* __restrict__ gsum, float* __restrict__ gsq)
{
    constexpr int KT = K / 32;
    constexpr int RB = K * 2 + 16;            // padded LDS row stride (bytes)
    __shared__ unsigned char sA[128 * RB];
    __shared__ float sS[128];
    __shared__ float sQ[128];

    const int tid  = threadIdx.x;
    const int lane = tid & 63;
    const int wv   = tid >> 6;
    const int m    = lane & 15;
    const int quad = lane >> 4;
    const int li   = lane & 15;
    const int sub  = lane >> 4;               // 0..3 (4 rows per gather pass)
    const int rowbase = blockIdx.x * 128 + wv * 32;

    if (tid < 128) { sS[tid] = 0.f; sQ[tid] = 0.f; }

    // ---- root-X prefetch: issued first, lands during the gather phase ----
    int rc[2];
#pragma unroll
    for (int st = 0; st < 2; ++st) {
        int r = rowbase + st * 16 + m;
        rc[st] = r < N_NODES ? r : N_NODES - 1;
    }
    bf16x8 xReg[2][KT];
    float4 xr[2][KT][2];
    if constexpr (L2) {
#pragma unroll
        for (int st = 0; st < 2; ++st) {
            const unsigned short* xp = xgB + (size_t)rc[st] * K + quad * 8;
#pragma unroll
            for (int kt = 0; kt < KT; ++kt)
                xReg[st][kt] = *(const bf16x8*)(xp + kt * 32);
        }
    } else {
#pragma unroll
        for (int st = 0; st < 2; ++st) {
            const float* xp = xgF + (size_t)rc[st] * K + quad * 8;
#pragma unroll
            for (int kt = 0; kt < KT; ++kt) {
                xr[st][kt][0] = *(const float4*)(xp + kt * 32);
                xr[st][kt][1] = *(const float4*)(xp + kt * 32 + 4);
            }
        }
    }

    // ---- rowptr for the wave's 32 rows: one coalesced load + shfl ----
    int rpv = rowptr[min(rowbase + min(lane, 32), N_NODES)];
    int bA[8], eA[8];
#pragma unroll
    for (int g = 0; g < 8; ++g) {
        bA[g] = __shfl(rpv, g * 4 + sub);
        eA[g] = __shfl(rpv, g * 4 + sub + 1);
    }

    // ---- gather phase: 2-stage pipeline over 8 passes ----
    int sN[8];
#pragma unroll
    for (int q = 0; q < 8; ++q) sN[q] = (bA[0] + q < eA[0]) ? ssrc[bA[0] + q] : 0;

    for (int g = 0; g < 8; ++g) {
        const int lrow = wv * 32 + g * 4 + sub;
        const int b = bA[g], e = eA[g];
        int sC[8];
#pragma unroll
        for (int q = 0; q < 8; ++q) sC[q] = sN[q];

        if constexpr (L2) {
            // issue this pass's feature loads
            bf16x8 v[8];
#pragma unroll
            for (int q = 0; q < 8; ++q)
                v[q] = *(const bf16x8*)(xgB + (size_t)sC[q] * K + li * 8);
            // prefetch next pass's indices (independent — overlaps v)
            if (g < 7) {
#pragma unroll
                for (int q = 0; q < 8; ++q)
                    sN[q] = (bA[g+1] + q < eA[g+1]) ? ssrc[bA[g+1] + q] : 0;
            }
            float acc[8] = {};
#pragma unroll
            for (int q = 0; q < 8; ++q) {
                float w = (b + q < e) ? 1.f : 0.f;
#pragma unroll
                for (int k = 0; k < 8; ++k)
                    acc[k] = fmaf(bf2f((unsigned short)v[q][k]), w, acc[k]);
            }
            // tail: deg > 8 (batched, as before)
            if (e > b + 8) {
                int s2[8];
#pragma unroll
                for (int q = 0; q < 8; ++q) s2[q] = (b + 8 + q < e) ? ssrc[b + 8 + q] : 0;
                for (int j = b + 8; j < e; j += 8) {
                    int nn[8];
                    const int jn = j + 8;
#pragma unroll
                    for (int q = 0; q < 8; ++q) nn[q] = (jn + q < e) ? ssrc[jn + q] : 0;
                    bf16x8 v2[8];
#pragma unroll
                    for (int q = 0; q < 8; ++q)
                        v2[q] = *(const bf16x8*)(xgB + (size_t)s2[q] * K + li * 8);
#pragma unroll
                    for (int q = 0; q < 8; ++q) {
                        float w = (j + q < e) ? 1.f : 0.f;
#pragma unroll
                        for (int k = 0; k < 8; ++k)
                            acc[k] = fmaf(bf2f((unsigned short)v2[q][k]), w, acc[k]);
                    }
#pragma unroll
                    for (int q = 0; q < 8; ++q) s2[q] = nn[q];
                }
            }
            bf16x8 o;
#pragma unroll
            for (int k = 0; k < 8; ++k) o[k] = (short)f2bf(acc[k]);
            *(bf16x8*)(sA + lrow * RB + li * 16) = o;
        } else {
            float4 v[8];
#pragma unroll
            for (int q = 0; q < 8; ++q)
                v[q] = ((const float4*)(xgF + (size_t)sC[q] * K))[li];
            if (g < 7) {
#pragma unroll
                for (int q = 0; q < 8; ++q)
                    sN[q] = (bA[g+1] + q < eA[g+1]) ? ssrc[bA[g+1] + q] : 0;
            }
            float4 a4 = {0.f, 0.f, 0.f, 0.f};
#pragma unroll
            for (int q = 0; q < 8; ++q) {
                float w = (b + q < e) ? 1.f : 0.f;
                a4.x = fmaf(v[q].x, w, a4.x);
                a4.y = fmaf(v[q].y, w, a4.y);
                a4.z = fmaf(v[q].z, w, a4.z);
                a4.w = fmaf(v[q].w, w, a4.w);
            }
            if (e > b + 8) {
                int s2[8];
#pragma unroll
                for (int q = 0; q < 8; ++q) s2[q] = (b + 8 + q < e) ? ssrc[b + 8 + q] : 0;
                for (int j = b + 8; j < e; j += 8) {
                    int nn[8];
                    const int jn = j + 8;
#pragma unroll
                    for (int q = 0; q < 8; ++q) nn[q] = (jn + q < e) ? ssrc[jn + q] : 0;
                    float4 v2[8];
#pragma unroll
                    for (int q = 0; q < 8; ++q)
                        v2[q] = ((const float4*)(xgF + (size_t)s2[q] * K))[li];
#pragma unroll
                    for (int q = 0; q < 8; ++q) {
                        float w = (j + q < e) ? 1.f : 0.f;
                        a4.x = fmaf(v2[q].x, w, a4.x);
                        a4.y = fmaf(v2[q].y, w, a4.y);
                        a4.z = fmaf(v2[q].z, w, a4.z);
                        a4.w = fmaf(v2[q].w, w, a4.w);
                    }
#pragma unroll
                    for (int q = 0; q < 8; ++q) s2[q] = nn[q];
                }
            }
            us4 o;
            o.x = f2bf(a4.x); o.y = f2bf(a4.y); o.z = f2bf(a4.z); o.w = f2bf(a4.w);
            *(us4*)(sA + lrow * RB + li * 8) = o;
        }
    }

    // L1: convert prefetched f32 root rows to bf16 fragments
    if constexpr (!L2) {
#pragma unroll
        for (int st = 0; st < 2; ++st)
#pragma unroll
            for (int kt = 0; kt < KT; ++kt) {
                xReg[st][kt][0] = (short)f2bf(xr[st][kt][0].x);
                xReg[st][kt][1] = (short)f2bf(xr[st][kt][0].y);
                xReg[st][kt][2] = (short)f2bf(xr[st][kt][0].z);
                xReg[st][kt][3] = (short)f2bf(xr[st][kt][0].w);
                xReg[st][kt][4] = (short)f2bf(xr[st][kt][1].x);
                xReg[st][kt][5] = (short)f2bf(xr[st][kt][1].y);
                xReg[st][kt][6] = (short)f2bf(xr[st][kt][1].z);
                xReg[st][kt][7] = (short)f2bf(xr[st][kt][1].w);
            }
    }

    // per-nt epilogue constants (col = nt*16 + m)
    float bcol[8], ccol[8];
#pragma unroll
    for (int nt = 0; nt < 8; ++nt) {
        bcol[nt] = bias[nt * 16 + m];
        if constexpr (L2) ccol[nt] = c2[nt * 16 + m];
    }

    __syncthreads();   // A-tile complete

    // ---- A fragments from LDS (padded stride: conflict-free) ----
    bf16x8 aReg[2][KT];
#pragma unroll
    for (int st = 0; st < 2; ++st) {
        const unsigned char* ap = sA + (wv * 32 + st * 16 + m) * RB + quad * 16;
#pragma unroll
        for (int kt = 0; kt < KT; ++kt)
            aReg[st][kt] = *(const bf16x8*)(ap + kt * 64);
    }

    // ---- K loop: weights from global (L2-hot) + MFMA ----
    f32x4 acc[2][8] = {};
#pragma unroll
    for (int kt = 0; kt < KT; ++kt) {
#pragma unroll
        for (int nt = 0; nt < 8; ++nt) {
            bf16x8 wl = Wlp[(nt * KT + kt) * 64 + lane];
#pragma unroll
            for (int st = 0; st < 2; ++st)
                acc[st][nt] = __builtin_amdgcn_mfma_f32_16x16x32_bf16(
                    aReg[st][kt], wl, acc[st][nt], 0, 0, 0);
            bf16x8 wr = Wrp[(nt * KT + kt) * 64 + lane];
#pragma unroll
            for (int st = 0; st < 2; ++st)
                acc[st][nt] = __builtin_amdgcn_mfma_f32_16x16x32_bf16(
                    xReg[st][kt], wr, acc[st][nt], 0, 0, 0);
        }
    }

    // ---- epilogue: C/D layout col = lane&15, row = quad*4 + reg ----
    float stS[8] = {}, stQ[8] = {};
#pragma unroll
    for (int st = 0; st < 2; ++st) {
        const int orow = rowbase + st * 16 + quad * 4;
        float dg[4];
        if constexpr (L2) {
#pragma unroll
            for (int r = 0; r < 4; ++r) {
                int rr = orow + r;
                dg[r] = (rr < N_NODES) ? degf[rr] : 0.f;
            }
        }
#pragma unroll
        for (int nt = 0; nt < 8; ++nt) {
            int col = nt * 16 + m;
#pragma unroll
            for (int r = 0; r < 4; ++r) {
                int rr = orow + r;
                if (rr < N_NODES) {
                    float base = L2 ? fmaf(dg[r], ccol[nt], bcol[nt]) : bcol[nt];
                    float v = fmaxf(acc[st][nt][r] + base, 0.f);
                    if constexpr (L2) outF[(size_t)rr * 128 + col] = v;
                    else              outB[(size_t)rr * 128 + col] = f2bf(v);
                    stS[nt] += v;
                    stQ[nt] = fmaf(v, v, stQ[nt]);
                }
            }
        }
    }

    // ---- stats reduce: registers -> LDS -> global replica (8 replicas) ----
#pragma unroll
    for (int nt = 0; nt < 8; ++nt) {
        atomicAdd(&sS[nt * 16 + m], stS[nt]);
        atomicAdd(&sQ[nt * 16 + m], stQ[nt]);
    }
    __syncthreads();
    const int rep = (blockIdx.x & 7) * 128;
    if (tid < 128) {
        atomicAdd(&gsum[rep + tid], sS[tid]);
        atomicAdd(&gsq[rep + tid],  sQ[tid]);
    }
}

// ---------------------------------------------------------------------------
// BN finalize: per-feature scale/shift (sums the 8 stats replicas).
// ---------------------------------------------------------------------------
__global__ void bn_finalize_kernel(
    const float* __restrict__ gsum, const float* __restrict__ gsq,
    const float* __restrict__ g, const float* __restrict__ be,
    float* __restrict__ scale, float* __restrict__ shift, float invN)
{
    int c = threadIdx.x;  // 128
    float s = 0.f, q = 0.f;
#pragma unroll
    for (int k = 0; k < 8; ++k) {
        s += gsum[k * 128 + c];
        q += gsq[k * 128 + c];
    }
    float mean = s * invN;
    float var  = fmaxf(q * invN - mean * mean, 0.f);
    float sc   = g[c] * rsqrtf(var + BN_EPS);
    scale[c] = sc;
    shift[c] = be[c] - mean * sc;
}

// BN1 fold constants: c2 = shift1@W2l ; crb = shift1@W2r + b2
__global__ void bn_fold_kernel(
    const float* __restrict__ shift1, const float* __restrict__ W2l,
    const float* __restrict__ W2r, const float* __restrict__ b2,
    float* __restrict__ c2, float* __restrict__ crb)
{
    int col = threadIdx.x;  // 128
    float a = 0.f, r = 0.f;
    for (int k = 0; k < 128; ++k) {
        float s = shift1[k];
        a = fmaf(s, W2l[(size_t)k * 128 + col], a);
        r = fmaf(s, W2r[(size_t)k * 128 + col], r);
    }
    c2[col]  = a;
    crb[col] = r + b2[col];
}

// ---------------------------------------------------------------------------
// Final BN apply + ReLU (in place on d_out).
// ---------------------------------------------------------------------------
__global__ __launch_bounds__(256) void bn_apply_relu_kernel(
    float* __restrict__ h, const float* __restrict__ scale,
    const float* __restrict__ shift, int n4)
{
    int i = blockIdx.x * 256 + threadIdx.x;
    if (i >= n4) return;
    int cb = i & 31;
    float4 v  = ((float4*)h)[i];
    float4 sc = ((const float4*)scale)[cb];
    float4 sh = ((const float4*)shift)[cb];
    v.x = fmaxf(fmaf(v.x, sc.x, sh.x), 0.f);
    v.y = fmaxf(fmaf(v.y, sc.y, sh.y), 0.f);
    v.z = fmaxf(fmaf(v.z, sc.z, sh.z), 0.f);
    v.w = fmaxf(fmaf(v.w, sc.w, sh.w), 0.f);
    ((float4*)h)[i] = v;
}

extern "C" void kernel_launch(void* const* d_in, const int* in_sizes, int n_in,
                              void* d_out, int out_size, void* d_ws, size_t ws_size,
                              hipStream_t stream) {
    const float* x   = (const float*)d_in[0];
    const int*   ei  = (const int*)d_in[1];
    const float* W1l = (const float*)d_in[2];
    const float* b1  = (const float*)d_in[3];
    const float* W1r = (const float*)d_in[4];
    const float* g1  = (const float*)d_in[5];
    const float* be1 = (const float*)d_in[6];
    const float* W2l = (const float*)d_in[7];
    const float* b2  = (const float*)d_in[8];
    const float* W2r = (const float*)d_in[9];
    const float* g2  = (const float*)d_in[10];
    const float* be2 = (const float*)d_in[11];
    float* out = (float*)d_out;

    const int N = N_NODES, E = N_EDGES;
    const int NB1 = (N + 1023) / 1024;          // 196 scan blocks
    const int nT  = (N + 127) / 128;            // 1563 fused blocks

    // Workspace layout (float units):
    float* ws     = (float*)d_ws;
    float* gsum1  = ws;          float* gsq1   = ws + 1024;   // 8 replicas x 128
    float* gsum2  = ws + 2048;   float* gsq2   = ws + 3072;
    float* scale1 = ws + 4096;   float* shift1 = ws + 4224;
    float* scale2 = ws + 4352;   float* shift2 = ws + 4480;
    float* c2v    = ws + 4608;   float* crb    = ws + 4736;
    short* W1lp = (short*)(ws + 5120);                        // 4096 f
    short* W1rp = (short*)(ws + 5120 + 4096);                 // 4096 f
    short* W2lp = (short*)(ws + 5120 + 8192);                 // 8192 f
    short* W2rp = (short*)(ws + 5120 + 16384);                // 8192 f
    int*   deg    = (int*)(ws + 29696);                       // N
    int*   part   = deg + N;                                  // N
    int*   bsum   = part + N;                                 // 1024
    int*   rowptr = bsum + 1024;                              // N+1 (pad 1024)
    int*   bcursor= rowptr + (N + 1024);                      // 256
    float* degf   = (float*)(bcursor + 256);                  // N
    int*   ssrc   = (int*)(degf + N);                         // E
    unsigned short* t1   = (unsigned short*)(ssrc + E);       // N*128 bf16
    unsigned* binned = (unsigned*)(t1 + (size_t)N * F_H);     // E u32

    // ---- Graph build + layer-1 weight pack ----
    hipMemsetAsync(ws, 0, 4096 * sizeof(float), stream);      // stats replicas
    hipMemsetAsync(deg, 0, (size_t)N * sizeof(int), stream);
    pack_weights_kernel<<<4, 256, 0, stream>>>(W1l, nullptr, W1lp, 2);
    pack_weights_kernel<<<4, 256, 0, stream>>>(W1r, nullptr, W1rp, 2);
    hist_kernel<<<(E + 255) / 256, 256, 0, stream>>>(ei, deg, E);
    scan1_kernel<<<NB1, 256, 0, stream>>>(deg, part, bsum, N);
    scan2_kernel<<<1, 256, 0, stream>>>(bsum, NB1);
    scan3_kernel<<<(N + 255) / 256, 256, 0, stream>>>(part, bsum, deg, rowptr,
                                                      bcursor, degf, N, E);
    bin_kernel<<<BINB, 256, 0, stream>>>(ei, bcursor, binned, E);
    scatter_kernel<<<NBUK, 256, 0, stream>>>(binned, rowptr, ssrc);

    // ---- Layer 1 (fused gather + GEMM + stats) ----
    fused_sage_kernel<F_IN, false><<<nT, 256, 0, stream>>>(
        x, nullptr, rowptr, ssrc,
        (const bf16x8*)W1lp, (const bf16x8*)W1rp, b1,
        nullptr, nullptr, nullptr, t1, gsum1, gsq1);
    bn_finalize_kernel<<<1, 128, 0, stream>>>(gsum1, gsq1, g1, be1,
                                              scale1, shift1, 1.f / N);

    // ---- Layer 2 (BN1 folded: scale1 into weights, shift1 into c2/crb) ----
    pack_weights_kernel<<<8, 256, 0, stream>>>(W2l, scale1, W2lp, 4);
    pack_weights_kernel<<<8, 256, 0, stream>>>(W2r, scale1, W2rp, 4);
    bn_fold_kernel<<<1, 128, 0, stream>>>(shift1, W2l, W2r, b2, c2v, crb);
    fused_sage_kernel<F_H, true><<<nT, 256, 0, stream>>>(
        nullptr, t1, rowptr, ssrc,
        (const bf16x8*)W2lp, (const bf16x8*)W2rp, crb,
        c2v, degf, out, nullptr, gsum2, gsq2);
    bn_finalize_kernel<<<1, 128, 0, stream>>>(gsum2, gsq2, g2, be2,
                                              scale2, shift2, 1.f / N);
    bn_apply_relu_kernel<<<(N * F_H / 4 + 255) / 256, 256, 0, stream>>>(
        out, scale2, shift2, N * F_H / 4);
}